// Round 2
// baseline (4274.458 us; speedup 1.0000x reference)
//
#include <hip/hip_runtime.h>

#define BATCH 128
#define SEQ   1024
#define NIN   7
#define NH    64
#define NG    256   // 4*NH
#define NOUT  500
#define RING  32    // h ring-buffer depth (steps between global flushes)

__device__ __forceinline__ float fast_sig(float x) {
    return __fdividef(1.0f, 1.0f + __expf(-x));
}
__device__ __forceinline__ float fast_tanh(float x) {
    // 2*sigmoid(2x)-1 : safe at extremes (no inf*0)
    return 2.0f * __fdividef(1.0f, 1.0f + __expf(-2.0f * x)) - 1.0f;
}

// One block per batch element. 512 threads: 2 threads per gate row (split-K
// over the 64-wide h dot product, combined with shfl_xor(1)).
// h ring-buffered in LDS, flushed to HBM every RING steps so the per-step
// __syncthreads never drains a global store.
__global__ __launch_bounds__(512) void lstm_kernel(
    const float* __restrict__ x,     // [B, T, 7]
    const float* __restrict__ W_ih,  // [256, 7]
    const float* __restrict__ W_hh,  // [256, 64]
    const float* __restrict__ b_ih,  // [256]
    const float* __restrict__ b_hh,  // [256]
    float* __restrict__ hout)        // [B*T, 64]
{
    const int b    = blockIdx.x;
    const int tid  = threadIdx.x;
    const int gate = tid >> 1;      // 0..255
    const int half = tid & 1;       // which 32-slice of h
    const int type = gate >> 6;     // 0:i 1:f 2:g 3:o
    const int idx  = tid & 63;      // hidden index for the (replicated) update

    __shared__ __align__(16) float xs[SEQ * NIN];    // 28 KB
    __shared__ __align__(16) float hs[NH];
    __shared__ __align__(16) float gs[NG];
    __shared__ __align__(16) float hring[RING][NH];  // 8 KB

    // stage this batch's whole input sequence (coalesced float4, once)
    {
        const float4* xb4 = (const float4*)(x + (size_t)b * SEQ * NIN);
        float4* xs4 = (float4*)xs;
        for (int i = tid; i < SEQ * NIN / 4; i += 512) xs4[i] = xb4[i];
    }

    // per-thread recurrent weights: my 32-slice of W_hh row `gate`
    float w[32];
    {
        const float* wrow = W_hh + gate * NH + half * 32;
        #pragma unroll
        for (int j = 0; j < 32; ++j) w[j] = wrow[j];
    }
    // input weights split 4/3 between the two halves (pad slot -> weight 0)
    float wi[4];
    #pragma unroll
    for (int k = 0; k < 4; ++k) {
        int c = half * 4 + k;
        wi[k] = (c < NIN) ? W_ih[gate * NIN + c] : 0.0f;
    }
    const float bias = half ? (b_ih[gate] + b_hh[gate]) : 0.0f;

    if (tid < NH) hs[tid] = 0.0f;
    float c = 0.0f;                  // replicated per wave for idx
    __syncthreads();

    float* hb = hout + (size_t)b * SEQ * NH;

    for (int t = 0; t < SEQ; ++t) {
        const float* xt = &xs[t * NIN];
        // --- gate phase: each thread does half the dot product ---
        float a0 = bias, a1 = 0.0f, a2 = 0.0f, a3 = 0.0f;
        #pragma unroll
        for (int k = 0; k < 4; ++k) {
            int cc = half * 4 + k;
            a0 = fmaf(wi[k], xt[cc < NIN ? cc : 0], a0);
        }
        #pragma unroll
        for (int j = 0; j < 32; j += 4) {
            float4 hv = *(const float4*)&hs[half * 32 + j];  // broadcast read
            a0 = fmaf(w[j+0], hv.x, a0);
            a1 = fmaf(w[j+1], hv.y, a1);
            a2 = fmaf(w[j+2], hv.z, a2);
            a3 = fmaf(w[j+3], hv.w, a3);
        }
        float s = (a0 + a1) + (a2 + a3);
        s += __shfl_xor(s, 1, 64);   // combine the two halves (same gate)
        float act = (type == 2) ? fast_tanh(s) : fast_sig(s);
        if (!half) gs[gate] = act;
        __syncthreads();

        // --- update phase: replicated across all 8 waves (no serialization) ---
        float iv = gs[idx], fv = gs[NH + idx], gv = gs[2*NH + idx], ov = gs[3*NH + idx];
        c = fmaf(fv, c, iv * gv);
        float h = ov * fast_tanh(c);
        if (tid < NH) {
            hs[tid] = h;
            hring[t & (RING - 1)][tid] = h;   // LDS, not global
        }
        __syncthreads();

        // --- flush ring to HBM every RING steps: one coalesced float4/thread ---
        if ((t & (RING - 1)) == (RING - 1)) {
            float4 v = ((const float4*)hring)[tid];       // 512 x 16B = 8 KB
            int trow = (t - (RING - 1)) + (tid >> 4);     // 16 float4 per step-row
            *(float4*)&hb[(size_t)trow * NH + (tid & 15) * 4] = v;
            // no extra barrier: ring slot 0 is only rewritten after the next
            // step's first __syncthreads
        }
    }
}

// FC: [B*T,64] @ [64,500]^T + b.  Block tile 64x128, thread tile 4x8, K fully resident.
#define MT 64
#define NT 128
#define HP 68   // padded row (float): 68 mod 32 = 4 -> <=2-way conflicts on b128 reads

__global__ __launch_bounds__(256) void fc_kernel(
    const float* __restrict__ hin,   // [B*T, 64]
    const float* __restrict__ W_fc,  // [500, 64]
    const float* __restrict__ b_fc,  // [500]
    float* __restrict__ out)         // [B*T, 500]
{
    const int mblk = blockIdx.x;
    const int nblk = blockIdx.y;
    const int tid  = threadIdx.x;
    const int tr   = tid >> 4;   // 0..15
    const int tc   = tid & 15;   // 0..15

    __shared__ __align__(16) float hsm[MT][HP];  // ~17 KB
    __shared__ __align__(16) float wsm[NT][HP];  // ~35 KB

    const float4* hsrc = (const float4*)(hin + (size_t)mblk * MT * NH);
    for (int i = tid; i < MT * (NH/4); i += 256) {
        int row = i >> 4, k4 = i & 15;
        *(float4*)&hsm[row][k4 * 4] = hsrc[i];
    }
    const int c0 = nblk * NT;
    const float4* wsrc = (const float4*)W_fc;
    for (int i = tid; i < NT * (NH/4); i += 256) {
        int row = i >> 4, k4 = i & 15;
        int col = c0 + row;
        float4 v = make_float4(0.f, 0.f, 0.f, 0.f);
        if (col < NOUT) v = wsrc[col * (NH/4) + k4];
        *(float4*)&wsm[row][k4 * 4] = v;
    }
    __syncthreads();

    float acc[4][8];
    #pragma unroll
    for (int r = 0; r < 4; ++r)
        #pragma unroll
        for (int cc = 0; cc < 8; ++cc) acc[r][cc] = 0.0f;

    #pragma unroll
    for (int k = 0; k < NH; k += 4) {
        float4 a[4];
        #pragma unroll
        for (int r = 0; r < 4; ++r) a[r] = *(const float4*)&hsm[tr * 4 + r][k];
        #pragma unroll
        for (int cc = 0; cc < 8; ++cc) {
            float4 wv = *(const float4*)&wsm[cc * 16 + tc][k];
            #pragma unroll
            for (int r = 0; r < 4; ++r) {
                acc[r][cc] = fmaf(a[r].x, wv.x, acc[r][cc]);
                acc[r][cc] = fmaf(a[r].y, wv.y, acc[r][cc]);
                acc[r][cc] = fmaf(a[r].z, wv.z, acc[r][cc]);
                acc[r][cc] = fmaf(a[r].w, wv.w, acc[r][cc]);
            }
        }
    }

    const size_t row0 = (size_t)mblk * MT + (size_t)tr * 4;
    #pragma unroll
    for (int r = 0; r < 4; ++r) {
        float* orow = out + (row0 + r) * NOUT;
        #pragma unroll
        for (int cc = 0; cc < 8; ++cc) {
            int col = c0 + cc * 16 + tc;
            if (col < NOUT) orow[col] = acc[r][cc] + b_fc[col];
        }
    }
}

extern "C" void kernel_launch(void* const* d_in, const int* in_sizes, int n_in,
                              void* d_out, int out_size, void* d_ws, size_t ws_size,
                              hipStream_t stream) {
    const float* x    = (const float*)d_in[0];
    const float* W_ih = (const float*)d_in[1];
    const float* W_hh = (const float*)d_in[2];
    const float* b_ih = (const float*)d_in[3];
    const float* b_hh = (const float*)d_in[4];
    const float* W_fc = (const float*)d_in[5];
    const float* b_fc = (const float*)d_in[6];
    float* out  = (float*)d_out;
    float* hbuf = (float*)d_ws;   // [B*T, 64] fp32 = 33.5 MB scratch

    lstm_kernel<<<dim3(BATCH), dim3(512), 0, stream>>>(x, W_ih, W_hh, b_ih, b_hh, hbuf);

    dim3 fgrid((BATCH * SEQ) / MT, (NOUT + NT - 1) / NT);
    fc_kernel<<<fgrid, dim3(256), 0, stream>>>(hbuf, W_fc, b_fc, out);
}

// Round 3
// 1141.899 us; speedup vs baseline: 3.7433x; 3.7433x over previous
//
#include <hip/hip_runtime.h>

#define BATCH 128
#define SEQ   1024
#define NIN   7
#define NH    64
#define NOUT  500

__device__ __forceinline__ float fast_sig(float x) {
    return __fdividef(1.0f, 1.0f + __expf(-x));
}
__device__ __forceinline__ float fast_tanh(float x) {
    // 2*sigmoid(2x)-1 : safe at extremes (no inf*0)
    return 2.0f * __fdividef(1.0f, 1.0f + __expf(-2.0f * x)) - 1.0f;
}

// One block per batch element, 512 threads. Lane group = 8 threads per hidden
// index j; each group computes ALL FOUR gates for j (8-way split-K over h,
// butterfly shfl_xor reduce) then updates c/h locally -> ONE barrier per step.
// hs double-buffered (merged phase would otherwise race). h ring-buffered
// 64-deep in LDS, flushed as one coalesced 8KB store every 32 steps (reuse
// distance 64 -> flush never races the single barrier).
__global__ __launch_bounds__(512) void lstm_kernel(
    const float* __restrict__ x,     // [B, T, 7]
    const float* __restrict__ W_ih,  // [256, 7]
    const float* __restrict__ W_hh,  // [256, 64]
    const float* __restrict__ b_ih,  // [256]
    const float* __restrict__ b_hh,  // [256]
    float* __restrict__ hout)        // [B*T, 64]
{
    const int b   = blockIdx.x;
    const int tid = threadIdx.x;
    const int j   = tid >> 3;   // hidden index 0..63
    const int s   = tid & 7;    // k-slice 0..7 (h[8s..8s+7])

    __shared__ __align__(16) float xs[SEQ * NIN];   // 28 KB
    __shared__ __align__(16) float hs[2][NH];
    __shared__ __align__(16) float ring[64][NH];    // 16 KB

    // stage this batch's whole input sequence once (coalesced float4)
    {
        const float4* xb4 = (const float4*)(x + (size_t)b * SEQ * NIN);
        float4* xs4 = (float4*)xs;
        for (int i = tid; i < SEQ * NIN / 4; i += 512) xs4[i] = xb4[i];
    }

    // recurrent weights: my 8-slice of W_hh row for each of my 4 gates
    float w[4][8];
    #pragma unroll
    for (int ty = 0; ty < 4; ++ty) {
        const float* wrow = W_hh + (ty * NH + j) * NH + s * 8;
        #pragma unroll
        for (int k = 0; k < 8; ++k) w[ty][k] = wrow[k];
    }
    // input weights: lane s handles input s (s==7 -> zero weight)
    const int xi = (s < NIN) ? s : 0;
    float wx[4], bias[4];
    #pragma unroll
    for (int ty = 0; ty < 4; ++ty) {
        wx[ty]   = (s < NIN) ? W_ih[(ty * NH + j) * NIN + s] : 0.0f;
        bias[ty] = (s == 0) ? (b_ih[ty * NH + j] + b_hh[ty * NH + j]) : 0.0f;
    }

    if (tid < NH) hs[0][tid] = 0.0f;
    float c = 0.0f;   // replicated across the 8 lanes of group j
    __syncthreads();

    float* hb = hout + (size_t)b * SEQ * NH;

    for (int t = 0; t < SEQ; ++t) {
        // flush previous 32 steps every 32 steps (slots safe for 64 steps)
        if ((t & 31) == 0 && t > 0) {
            const int tf0 = t - 32;
            float4 v = ((const float4*)&ring[tf0 & 63][0])[tid];
            *(float4*)&hb[(size_t)tf0 * NH + tid * 4] = v;
        }

        const float xv = xs[t * NIN + xi];
        const float* hrd = hs[t & 1];
        float4 h0 = *(const float4*)&hrd[s * 8];
        float4 h1 = *(const float4*)&hrd[s * 8 + 4];

        float a0 = fmaf(wx[0], xv, bias[0]);
        float a1 = fmaf(wx[1], xv, bias[1]);
        float a2 = fmaf(wx[2], xv, bias[2]);
        float a3 = fmaf(wx[3], xv, bias[3]);
        a0 = fmaf(w[0][0], h0.x, a0); a0 = fmaf(w[0][1], h0.y, a0);
        a0 = fmaf(w[0][2], h0.z, a0); a0 = fmaf(w[0][3], h0.w, a0);
        a0 = fmaf(w[0][4], h1.x, a0); a0 = fmaf(w[0][5], h1.y, a0);
        a0 = fmaf(w[0][6], h1.z, a0); a0 = fmaf(w[0][7], h1.w, a0);
        a1 = fmaf(w[1][0], h0.x, a1); a1 = fmaf(w[1][1], h0.y, a1);
        a1 = fmaf(w[1][2], h0.z, a1); a1 = fmaf(w[1][3], h0.w, a1);
        a1 = fmaf(w[1][4], h1.x, a1); a1 = fmaf(w[1][5], h1.y, a1);
        a1 = fmaf(w[1][6], h1.z, a1); a1 = fmaf(w[1][7], h1.w, a1);
        a2 = fmaf(w[2][0], h0.x, a2); a2 = fmaf(w[2][1], h0.y, a2);
        a2 = fmaf(w[2][2], h0.z, a2); a2 = fmaf(w[2][3], h0.w, a2);
        a2 = fmaf(w[2][4], h1.x, a2); a2 = fmaf(w[2][5], h1.y, a2);
        a2 = fmaf(w[2][6], h1.z, a2); a2 = fmaf(w[2][7], h1.w, a2);
        a3 = fmaf(w[3][0], h0.x, a3); a3 = fmaf(w[3][1], h0.y, a3);
        a3 = fmaf(w[3][2], h0.z, a3); a3 = fmaf(w[3][3], h0.w, a3);
        a3 = fmaf(w[3][4], h1.x, a3); a3 = fmaf(w[3][5], h1.y, a3);
        a3 = fmaf(w[3][6], h1.z, a3); a3 = fmaf(w[3][7], h1.w, a3);

        // butterfly reduce over the 8 lanes of this group
        #pragma unroll
        for (int m = 1; m <= 4; m <<= 1) {
            a0 += __shfl_xor(a0, m);
            a1 += __shfl_xor(a1, m);
            a2 += __shfl_xor(a2, m);
            a3 += __shfl_xor(a3, m);
        }

        float iv = fast_sig(a0), fv = fast_sig(a1);
        float gv = fast_tanh(a2), ov = fast_sig(a3);
        c = fmaf(fv, c, iv * gv);
        float h = ov * fast_tanh(c);
        if (s == 0) {
            hs[(t + 1) & 1][j] = h;
            ring[t & 63][j] = h;
        }
        __syncthreads();
    }
    {   // final flush: last 32 steps
        const int tf0 = SEQ - 32;
        float4 v = ((const float4*)&ring[tf0 & 63][0])[tid];
        *(float4*)&hb[(size_t)tf0 * NH + tid * 4] = v;
    }
}

// FC: [B*T,64] @ [64,500]^T + b.  Block tile 64x128, thread tile 4x8.
// r2 lesson: full K-unroll spilled (VGPR=256, 8.7GB scratch traffic).
// Fix: bounded unroll + VGPR cap via launch_bounds(256,3).
#define MT 64
#define NT 128
#define HP 68   // padded row: rows land on distinct bank groups, b128-aligned

__global__ __launch_bounds__(256, 3) void fc_kernel(
    const float* __restrict__ hin,   // [B*T, 64]
    const float* __restrict__ W_fc,  // [500, 64]
    const float* __restrict__ b_fc,  // [500]
    float* __restrict__ out)         // [B*T, 500]
{
    const int mblk = blockIdx.x;
    const int nblk = blockIdx.y;
    const int tid  = threadIdx.x;
    const int tr   = tid >> 4;   // 0..15
    const int tc   = tid & 15;   // 0..15

    __shared__ __align__(16) float hsm[MT][HP];  // ~17 KB
    __shared__ __align__(16) float wsm[NT][HP];  // ~35 KB

    const float4* hsrc = (const float4*)(hin + (size_t)mblk * MT * NH);
    for (int i = tid; i < MT * (NH/4); i += 256) {
        int row = i >> 4, k4 = i & 15;
        *(float4*)&hsm[row][k4 * 4] = hsrc[i];
    }
    const int c0 = nblk * NT;
    const float4* wsrc = (const float4*)W_fc;
    for (int i = tid; i < NT * (NH/4); i += 256) {
        int row = i >> 4, k4 = i & 15;
        int col = c0 + row;
        float4 v = make_float4(0.f, 0.f, 0.f, 0.f);
        if (col < NOUT) v = wsrc[col * (NH/4) + k4];
        *(float4*)&wsm[row][k4 * 4] = v;
    }
    __syncthreads();

    float acc[4][8];
    #pragma unroll
    for (int r = 0; r < 4; ++r)
        #pragma unroll
        for (int cc = 0; cc < 8; ++cc) acc[r][cc] = 0.0f;

    #pragma unroll 2
    for (int kc = 0; kc < 16; ++kc) {
        const int k = kc * 4;
        float4 a0 = *(const float4*)&hsm[tr * 4 + 0][k];
        float4 a1 = *(const float4*)&hsm[tr * 4 + 1][k];
        float4 a2 = *(const float4*)&hsm[tr * 4 + 2][k];
        float4 a3 = *(const float4*)&hsm[tr * 4 + 3][k];
        #pragma unroll
        for (int cc = 0; cc < 8; ++cc) {
            float4 wv = *(const float4*)&wsm[cc * 16 + tc][k];
            acc[0][cc] = fmaf(a0.x, wv.x, acc[0][cc]);
            acc[0][cc] = fmaf(a0.y, wv.y, acc[0][cc]);
            acc[0][cc] = fmaf(a0.z, wv.z, acc[0][cc]);
            acc[0][cc] = fmaf(a0.w, wv.w, acc[0][cc]);
            acc[1][cc] = fmaf(a1.x, wv.x, acc[1][cc]);
            acc[1][cc] = fmaf(a1.y, wv.y, acc[1][cc]);
            acc[1][cc] = fmaf(a1.z, wv.z, acc[1][cc]);
            acc[1][cc] = fmaf(a1.w, wv.w, acc[1][cc]);
            acc[2][cc] = fmaf(a2.x, wv.x, acc[2][cc]);
            acc[2][cc] = fmaf(a2.y, wv.y, acc[2][cc]);
            acc[2][cc] = fmaf(a2.z, wv.z, acc[2][cc]);
            acc[2][cc] = fmaf(a2.w, wv.w, acc[2][cc]);
            acc[3][cc] = fmaf(a3.x, wv.x, acc[3][cc]);
            acc[3][cc] = fmaf(a3.y, wv.y, acc[3][cc]);
            acc[3][cc] = fmaf(a3.z, wv.z, acc[3][cc]);
            acc[3][cc] = fmaf(a3.w, wv.w, acc[3][cc]);
        }
    }

    const size_t row0 = (size_t)mblk * MT + (size_t)tr * 4;
    #pragma unroll
    for (int r = 0; r < 4; ++r) {
        float* orow = out + (row0 + r) * NOUT;
        #pragma unroll
        for (int cc = 0; cc < 8; ++cc) {
            int col = c0 + cc * 16 + tc;
            if (col < NOUT) orow[col] = acc[r][cc] + b_fc[col];
        }
    }
}

extern "C" void kernel_launch(void* const* d_in, const int* in_sizes, int n_in,
                              void* d_out, int out_size, void* d_ws, size_t ws_size,
                              hipStream_t stream) {
    const float* x    = (const float*)d_in[0];
    const float* W_ih = (const float*)d_in[1];
    const float* W_hh = (const float*)d_in[2];
    const float* b_ih = (const float*)d_in[3];
    const float* b_hh = (const float*)d_in[4];
    const float* W_fc = (const float*)d_in[5];
    const float* b_fc = (const float*)d_in[6];
    float* out  = (float*)d_out;
    float* hbuf = (float*)d_ws;   // [B*T, 64] fp32 = 33.5 MB scratch

    lstm_kernel<<<dim3(BATCH), dim3(512), 0, stream>>>(x, W_ih, W_hh, b_ih, b_hh, hbuf);

    dim3 fgrid((BATCH * SEQ) / MT, (NOUT + NT - 1) / NT);
    fc_kernel<<<fgrid, dim3(256), 0, stream>>>(hbuf, W_fc, b_fc, out);
}

// Round 4
// 837.994 us; speedup vs baseline: 5.1008x; 1.3627x over previous
//
#include <hip/hip_runtime.h>

#define BATCH 128
#define SEQ   1024
#define NIN   7
#define NH    64
#define NOUT  500

__device__ __forceinline__ float fast_sig(float x) {
    return __fdividef(1.0f, 1.0f + __expf(-x));
}
__device__ __forceinline__ float fast_tanh(float x) {
    return 2.0f * __fdividef(1.0f, 1.0f + __expf(-2.0f * x)) - 1.0f;
}

// quad-level butterfly add via DPP quad_perm: VALU op, no DS pipe (r3 lesson:
// __shfl_xor = ds_bpermute; 96 DS ops/CU/step dominated the LSTM).
template<int CTRL>
__device__ __forceinline__ float dpp_add(float v) {
    int p = __builtin_amdgcn_update_dpp(0, __float_as_int(v), CTRL, 0xF, 0xF, true);
    return v + __int_as_float(p);
}
// xor1 within quad = quad_perm[1,0,3,2] = 0xB1 ; xor2 = quad_perm[2,3,0,1] = 0x4E

// One block per batch element, 256 threads (4 waves).
// Group = quad of lanes per hidden j; lane s (0..3) holds k-slice h[16s..16s+15]
// for all 4 gates of j. Reduce = 2 DPP adds. One __syncthreads per step.
__global__ __launch_bounds__(256, 1) void lstm_kernel(
    const float* __restrict__ x,     // [B, T, 7]
    const float* __restrict__ W_ih,  // [256, 7]
    const float* __restrict__ W_hh,  // [256, 64]
    const float* __restrict__ b_ih,  // [256]
    const float* __restrict__ b_hh,  // [256]
    float* __restrict__ hout)        // [B*T, 64]
{
    const int b   = blockIdx.x;
    const int tid = threadIdx.x;
    const int j   = tid >> 2;   // hidden index 0..63
    const int s   = tid & 3;    // k-slice 0..3 (h[16s..16s+15])

    __shared__ __align__(16) float xs[SEQ * NIN];   // 28 KB
    __shared__ __align__(16) float hs[2][NH];
    __shared__ __align__(16) float ring[64][NH];    // 16 KB

    // stage the whole input sequence once (coalesced float4; 1792/256 = 7 each)
    {
        const float4* xb4 = (const float4*)(x + (size_t)b * SEQ * NIN);
        float4* xs4 = (float4*)xs;
        #pragma unroll
        for (int q = 0; q < 7; ++q) xs4[tid + q * 256] = xb4[tid + q * 256];
    }

    // recurrent weights: my 16-slice of W_hh row for each of my 4 gates
    float w[4][16];
    #pragma unroll
    for (int ty = 0; ty < 4; ++ty) {
        const float4* wrow = (const float4*)(W_hh + (ty * NH + j) * NH + s * 16);
        #pragma unroll
        for (int q = 0; q < 4; ++q) {
            float4 v = wrow[q];
            w[ty][q*4+0] = v.x; w[ty][q*4+1] = v.y;
            w[ty][q*4+2] = v.z; w[ty][q*4+3] = v.w;
        }
    }
    // input weights: lane s covers inputs s and s+4 (s==3: only input 3)
    const int x0 = s;
    const int x1 = (s < 3) ? s + 4 : s;   // s==3 re-reads x[3] with weight 0
    float wx0[4], wx1[4], bias[4];
    #pragma unroll
    for (int ty = 0; ty < 4; ++ty) {
        wx0[ty]  = W_ih[(ty * NH + j) * NIN + x0];
        wx1[ty]  = (s < 3) ? W_ih[(ty * NH + j) * NIN + x1] : 0.0f;
        bias[ty] = (s == 0) ? (b_ih[ty * NH + j] + b_hh[ty * NH + j]) : 0.0f;
    }

    if (tid < NH) hs[0][tid] = 0.0f;
    float c = 0.0f;   // replicated across the 4 lanes of group j
    __syncthreads();

    float* hb = hout + (size_t)b * SEQ * NH;

    for (int t = 0; t < SEQ; ++t) {
        // flush previous 32 steps every 32 steps (ring slots live 64 steps)
        if ((t & 31) == 0 && t) {
            const int tf0 = t - 32;
            const float4* rp = (const float4*)&ring[tf0 & 63][0];
            float4* gp = (float4*)&hb[(size_t)tf0 * NH];
            float4 v0 = rp[tid * 2], v1 = rp[tid * 2 + 1];
            gp[tid * 2] = v0; gp[tid * 2 + 1] = v1;
        }

        // h slice (issue early; x-FMAs overlap the LDS latency)
        const float4* hp = (const float4*)&hs[t & 1][s * 16];
        float4 h0 = hp[0], h1 = hp[1], h2 = hp[2], h3 = hp[3];
        const float xa = xs[t * NIN + x0];
        const float xb = xs[t * NIN + x1];

        float hv[16] = {h0.x,h0.y,h0.z,h0.w, h1.x,h1.y,h1.z,h1.w,
                        h2.x,h2.y,h2.z,h2.w, h3.x,h3.y,h3.z,h3.w};

        float a0 = fmaf(wx0[0], xa, bias[0]);
        float a1 = fmaf(wx0[1], xa, bias[1]);
        float a2 = fmaf(wx0[2], xa, bias[2]);
        float a3 = fmaf(wx0[3], xa, bias[3]);
        a0 = fmaf(wx1[0], xb, a0);
        a1 = fmaf(wx1[1], xb, a1);
        a2 = fmaf(wx1[2], xb, a2);
        a3 = fmaf(wx1[3], xb, a3);
        #pragma unroll
        for (int k = 0; k < 16; ++k) {
            const float hk = hv[k];
            a0 = fmaf(w[0][k], hk, a0);
            a1 = fmaf(w[1][k], hk, a1);
            a2 = fmaf(w[2][k], hk, a2);
            a3 = fmaf(w[3][k], hk, a3);
        }

        // quad reduce: 2 DPP adds per gate (VALU pipe only)
        a0 = dpp_add<0xB1>(a0); a0 = dpp_add<0x4E>(a0);
        a1 = dpp_add<0xB1>(a1); a1 = dpp_add<0x4E>(a1);
        a2 = dpp_add<0xB1>(a2); a2 = dpp_add<0x4E>(a2);
        a3 = dpp_add<0xB1>(a3); a3 = dpp_add<0x4E>(a3);

        const float iv = fast_sig(a0), fv = fast_sig(a1);
        const float gv = fast_tanh(a2), ov = fast_sig(a3);
        c = fmaf(fv, c, iv * gv);
        const float h = ov * fast_tanh(c);
        if (s == 0) {
            hs[(t + 1) & 1][j] = h;
            ring[t & 63][j] = h;
        }
        __syncthreads();
    }
    {   // final flush: last 32 steps
        const int tf0 = SEQ - 32;
        const float4* rp = (const float4*)&ring[tf0 & 63][0];
        float4* gp = (float4*)&hb[(size_t)tf0 * NH];
        float4 v0 = rp[tid * 2], v1 = rp[tid * 2 + 1];
        gp[tid * 2] = v0; gp[tid * 2 + 1] = v1;
    }
}

// ---------------- FC via bf16 MFMA with hi/lo split-float ----------------
// out = h @ W^T + b. A=[131072,64] fp32 -> (hi+lo) bf16; B=W_fc[500,64] same.
// A*B ~= Ah*Bh + Ah*Bl + Al*Bh  (lo*lo dropped; rel err ~2^-17 => fp32-grade).
// Block tile 128x64, 4 waves in 2x2, per wave 4x2 tiles of 16x16, K=64 (2 kt).
// LDS XOR-swizzle (T2): row-major K=128B rows would put all 16 frag lanes in
// one bank; slot ^= (row&7) spreads them (G4).

typedef __attribute__((ext_vector_type(8))) short s16x8;
typedef __attribute__((ext_vector_type(4))) float f32x4;

__device__ __forceinline__ ushort f2bf_rn(float f) {
    unsigned x = __float_as_uint(f);
    unsigned r = x + 0x7FFFu + ((x >> 16) & 1u);
    return (ushort)(r >> 16);
}
__device__ __forceinline__ float bf2f(ushort u) {
    return __uint_as_float(((unsigned)u) << 16);
}

#define FC_M 128
#define FC_N 64

__global__ __launch_bounds__(256, 2) void fc_mfma_kernel(
    const float* __restrict__ hin,   // [B*T, 64] fp32
    const float* __restrict__ W_fc,  // [500, 64]
    const float* __restrict__ b_fc,  // [500]
    float* __restrict__ out)         // [B*T, 500]
{
    const int M0  = blockIdx.x * FC_M;
    const int N0  = blockIdx.y * FC_N;
    const int tid = threadIdx.x;
    const int l   = tid & 63;
    const int wid = tid >> 6;
    const int wr  = wid >> 1;   // 0..1 (row half)
    const int wc  = wid & 1;    // 0..1 (col half)

    __shared__ __align__(16) ushort Ah[FC_M * 64], Al[FC_M * 64];  // 16KB each
    __shared__ __align__(16) ushort Bh[FC_N * 64], Bl[FC_N * 64];  // 8KB each

    // ---- stage A: 128 rows x 8 kslots (8 bf16 per slot); 4 slots/thread ----
    #pragma unroll
    for (int q = 0; q < 4; ++q) {
        int f = tid + q * 256;
        int row = f >> 3, ks = f & 7;
        const float* src = hin + (size_t)(M0 + row) * 64 + ks * 8;
        float4 v0 = *(const float4*)src;
        float4 v1 = *(const float4*)(src + 4);
        float fv[8] = {v0.x,v0.y,v0.z,v0.w, v1.x,v1.y,v1.z,v1.w};
        unsigned hi2[4], lo2[4];
        #pragma unroll
        for (int i = 0; i < 4; ++i) {
            ushort ha = f2bf_rn(fv[2*i]),   hb = f2bf_rn(fv[2*i+1]);
            ushort la = f2bf_rn(fv[2*i]   - bf2f(ha));
            ushort lb = f2bf_rn(fv[2*i+1] - bf2f(hb));
            hi2[i] = (unsigned)ha | ((unsigned)hb << 16);
            lo2[i] = (unsigned)la | ((unsigned)lb << 16);
        }
        int slot = row * 8 + (ks ^ (row & 7));
        *(uint4*)&Ah[slot * 8] = make_uint4(hi2[0], hi2[1], hi2[2], hi2[3]);
        *(uint4*)&Al[slot * 8] = make_uint4(lo2[0], lo2[1], lo2[2], lo2[3]);
    }
    // ---- stage B: 64 cols x 8 kslots; 2 slots/thread; col>=500 -> zeros ----
    #pragma unroll
    for (int q = 0; q < 2; ++q) {
        int f = tid + q * 256;
        int row = f >> 3, ks = f & 7;     // row = local out-col
        int col = N0 + row;
        float fv[8] = {0,0,0,0,0,0,0,0};
        if (col < NOUT) {
            const float* src = W_fc + (size_t)col * 64 + ks * 8;
            float4 v0 = *(const float4*)src;
            float4 v1 = *(const float4*)(src + 4);
            fv[0]=v0.x; fv[1]=v0.y; fv[2]=v0.z; fv[3]=v0.w;
            fv[4]=v1.x; fv[5]=v1.y; fv[6]=v1.z; fv[7]=v1.w;
        }
        unsigned hi2[4], lo2[4];
        #pragma unroll
        for (int i = 0; i < 4; ++i) {
            ushort ha = f2bf_rn(fv[2*i]),   hb = f2bf_rn(fv[2*i+1]);
            ushort la = f2bf_rn(fv[2*i]   - bf2f(ha));
            ushort lb = f2bf_rn(fv[2*i+1] - bf2f(hb));
            hi2[i] = (unsigned)ha | ((unsigned)hb << 16);
            lo2[i] = (unsigned)la | ((unsigned)lb << 16);
        }
        int slot = row * 8 + (ks ^ (row & 7));
        *(uint4*)&Bh[slot * 8] = make_uint4(hi2[0], hi2[1], hi2[2], hi2[3]);
        *(uint4*)&Bl[slot * 8] = make_uint4(lo2[0], lo2[1], lo2[2], lo2[3]);
    }
    __syncthreads();

    // ---- MFMA: per wave 4(row-tiles) x 2(col-tiles), K = 2 kt of 32 ----
    f32x4 acc[4][2];
    #pragma unroll
    for (int tm = 0; tm < 4; ++tm)
        #pragma unroll
        for (int tn = 0; tn < 2; ++tn) acc[tm][tn] = (f32x4){0.f, 0.f, 0.f, 0.f};

    #pragma unroll
    for (int kt = 0; kt < 2; ++kt) {
        const int ks = kt * 4 + (l >> 4);   // lane's k-chunk slot
        s16x8 ah[4], al[4], bh[2], bl[2];
        #pragma unroll
        for (int tm = 0; tm < 4; ++tm) {
            int row = wr * 64 + tm * 16 + (l & 15);
            int sl = row * 64 + (ks ^ (row & 7)) * 8;
            ah[tm] = *(const s16x8*)&Ah[sl];
            al[tm] = *(const s16x8*)&Al[sl];
        }
        #pragma unroll
        for (int tn = 0; tn < 2; ++tn) {
            int row = wc * 32 + tn * 16 + (l & 15);
            int sl = row * 64 + (ks ^ (row & 7)) * 8;
            bh[tn] = *(const s16x8*)&Bh[sl];
            bl[tn] = *(const s16x8*)&Bl[sl];
        }
        #pragma unroll
        for (int tm = 0; tm < 4; ++tm)
            #pragma unroll
            for (int tn = 0; tn < 2; ++tn) {
                acc[tm][tn] = __builtin_amdgcn_mfma_f32_16x16x32_bf16(ah[tm], bh[tn], acc[tm][tn], 0, 0, 0);
                acc[tm][tn] = __builtin_amdgcn_mfma_f32_16x16x32_bf16(ah[tm], bl[tn], acc[tm][tn], 0, 0, 0);
                acc[tm][tn] = __builtin_amdgcn_mfma_f32_16x16x32_bf16(al[tm], bh[tn], acc[tm][tn], 0, 0, 0);
            }
    }

    // ---- epilogue: D lane map col=l&15, row=4*(l>>4)+r (m89-verified) ----
    #pragma unroll
    for (int tn = 0; tn < 2; ++tn) {
        int col = N0 + wc * 32 + tn * 16 + (l & 15);
        if (col >= NOUT) continue;
        float bias = b_fc[col];
        #pragma unroll
        for (int tm = 0; tm < 4; ++tm) {
            int row = M0 + wr * 64 + tm * 16 + (l >> 4) * 4;
            #pragma unroll
            for (int r = 0; r < 4; ++r)
                out[(size_t)(row + r) * NOUT + col] = acc[tm][tn][r] + bias;
        }
    }
}

extern "C" void kernel_launch(void* const* d_in, const int* in_sizes, int n_in,
                              void* d_out, int out_size, void* d_ws, size_t ws_size,
                              hipStream_t stream) {
    const float* x    = (const float*)d_in[0];
    const float* W_ih = (const float*)d_in[1];
    const float* W_hh = (const float*)d_in[2];
    const float* b_ih = (const float*)d_in[3];
    const float* b_hh = (const float*)d_in[4];
    const float* W_fc = (const float*)d_in[5];
    const float* b_fc = (const float*)d_in[6];
    float* out  = (float*)d_out;
    float* hbuf = (float*)d_ws;   // [B*T, 64] fp32 = 33.5 MB scratch

    lstm_kernel<<<dim3(BATCH), dim3(256), 0, stream>>>(x, W_ih, W_hh, b_ih, b_hh, hbuf);

    dim3 fgrid((BATCH * SEQ) / FC_M, (NOUT + FC_N - 1) / FC_N);   // (1024, 8)
    fc_mfma_kernel<<<fgrid, dim3(256), 0, stream>>>(hbuf, W_fc, b_fc, out);
}